// Round 8
// baseline (559.349 us; speedup 1.0000x reference)
//
#include <hip/hip_runtime.h>
#include <hip/hip_bf16.h>
#include <stdint.h>

// MoE: N=8192 tokens, D=2048, E=8 experts, top-2 routing.
// prep (gate: zero-out-row + choice+weights + fused x->bf16 | W->bf16) ->
// build_lists (1 block, int4 ballot scatter, zero atomics) -> grouped bf16 MFMA
// GEMM, m97 structure: 128x128 tile, 4 waves, single-buffered 33 KB LDS
// (4 blocks/CU cross-block stall hiding) + T5 setprio on the compute cluster,
// XCD-chunked + 4x4-supergroup ordering, fused bias+ReLU+gate-weight epilogue,
// fp32 atomicAdd into out (zeroed by prep). Workspace ~101.5 MB (known-safe).

#define N_TOK 8192
#define DIM   2048
#define NEXP  8

#define BM 128
#define BN 128
#define BK 64
#define KT (DIM / BK)   // 32 K-steps

typedef __attribute__((ext_vector_type(8))) short short8;
typedef __attribute__((ext_vector_type(4))) float f32x4;

// ---- workspace layout (bytes) ----
#define OFF_CNT   0                                   // 8 ints
#define OFF_CH    128                                 // N_TOK ints
#define OFF_GW    (OFF_CH  + 4*N_TOK)                 // 2*N_TOK floats
#define OFF_TOK   (OFF_GW  + 8*N_TOK)                 // NEXP*N_TOK ints
#define OFF_WL    (OFF_TOK + 4*N_TOK*NEXP)            // NEXP*N_TOK floats
#define OFF_XB    (OFF_WL  + 4*N_TOK*NEXP)            // N*D bf16 (34 MB)
#define OFF_WB    (OFF_XB + (size_t)N_TOK*DIM*2)      // E*D*D bf16 (67 MB)
// end ~= 101.5 MB

__device__ __forceinline__ void gload_lds16(const void* g, void* l) {
  __builtin_amdgcn_global_load_lds(
      (const __attribute__((address_space(1))) void*)g,
      (__attribute__((address_space(3))) void*)l, 16, 0, 0);
}

// ---------------- prep: blocks [0,2048) = gate (+ x->bf16 + out-zero);
//                  blocks [2048,4096) = W->bf16 ----------------------------------
__global__ __launch_bounds__(256) void prep_kernel(
    const float* __restrict__ x, const float* __restrict__ We,
    const float* __restrict__ wg, const float* __restrict__ bg,
    __hip_bfloat16* __restrict__ xb, __hip_bfloat16* __restrict__ wb,
    int* __restrict__ choice, float* __restrict__ gw, float* __restrict__ out) {
  if (blockIdx.x >= N_TOK / 4) {
    const int n4 = NEXP * DIM * DIM / 4;
    const int stride = 2048 * 256;
    for (int i = (blockIdx.x - N_TOK / 4) * 256 + threadIdx.x; i < n4; i += stride) {
      float4 v = reinterpret_cast<const float4*>(We)[i];
      union { ushort4 u; __hip_bfloat16 h[4]; } cv;
      cv.h[0] = __float2bfloat16(v.x);
      cv.h[1] = __float2bfloat16(v.y);
      cv.h[2] = __float2bfloat16(v.z);
      cv.h[3] = __float2bfloat16(v.w);
      reinterpret_cast<ushort4*>(wb)[i] = cv.u;
    }
    return;
  }
  // ---- gating: one wave per token, fp32; fused x->bf16 cast + out-row zeroing ----
  const int wave = threadIdx.x >> 6;
  const int lane = threadIdx.x & 63;
  const int t = blockIdx.x * 4 + wave;
  const float4* xr = reinterpret_cast<const float4*>(x + (size_t)t * DIM);
  ushort4* xo = reinterpret_cast<ushort4*>(xb + (size_t)t * DIM);
  float4* oz = reinterpret_cast<float4*>(out + (size_t)t * DIM);
  const float4 zero4 = {0.f, 0.f, 0.f, 0.f};
#pragma unroll
  for (int j = 0; j < DIM / 4 / 64; ++j)       // zero this token's out row (8 KB)
    oz[lane + 64 * j] = zero4;
  float acc[NEXP];
#pragma unroll
  for (int e = 0; e < NEXP; ++e) acc[e] = 0.f;
#pragma unroll
  for (int j = 0; j < DIM / 4 / 64; ++j) {     // 8 iters
    float4 xv = xr[lane + 64 * j];
    union { ushort4 u; __hip_bfloat16 h[4]; } cv;
    cv.h[0] = __float2bfloat16(xv.x);
    cv.h[1] = __float2bfloat16(xv.y);
    cv.h[2] = __float2bfloat16(xv.z);
    cv.h[3] = __float2bfloat16(xv.w);
    xo[lane + 64 * j] = cv.u;
#pragma unroll
    for (int e = 0; e < NEXP; ++e) {
      float4 gv = reinterpret_cast<const float4*>(wg + (size_t)e * DIM)[lane + 64 * j];
      acc[e] += xv.x * gv.x + xv.y * gv.y + xv.z * gv.z + xv.w * gv.w;
    }
  }
#pragma unroll
  for (int e = 0; e < NEXP; ++e) {
    float v = acc[e];
#pragma unroll
    for (int off = 32; off > 0; off >>= 1) v += __shfl_down(v, off);
    acc[e] = v;
  }
  if (lane == 0) {
    float lg[NEXP];
#pragma unroll
    for (int e = 0; e < NEXP; ++e) lg[e] = acc[e] + bg[e];
    float m = lg[0];
#pragma unroll
    for (int e = 1; e < NEXP; ++e) m = fmaxf(m, lg[e]);
    float s = 0.f, w[NEXP];
#pragma unroll
    for (int e = 0; e < NEXP; ++e) { w[e] = expf(lg[e] - m); s += w[e]; }
    float inv = 1.f / s;
    int i0 = 0;
#pragma unroll
    for (int e = 1; e < NEXP; ++e) if (lg[e] > lg[i0]) i0 = e;
    int i1 = -1;
#pragma unroll
    for (int e = 0; e < NEXP; ++e)
      if (e != i0 && (i1 < 0 || lg[e] > lg[i1])) i1 = e;
    choice[t] = i0 | (i1 << 8);
    gw[2 * t]     = w[i0] * inv;
    gw[2 * t + 1] = w[i1] * inv;
  }
}

// ---------------- build lists: 1 block, 512 threads; wave w = expert w ------------
// int4-vectorized ballot scatter (32 iters). List order within an expert is
// arbitrary (each entry carries its weight). Zero atomics, zero LDS.
__global__ __launch_bounds__(512) void build_lists(
    const int* __restrict__ choice, const float* __restrict__ gw,
    int* __restrict__ cnt, int* __restrict__ toklist, float* __restrict__ wlist) {
  const int w = threadIdx.x >> 6;
  const int lane = threadIdx.x & 63;
  const unsigned long long lmask = (lane == 0) ? 0ull : (~0ull >> (64 - lane));
  const int4* ch4 = reinterpret_cast<const int4*>(choice);
  const float2* gw2 = reinterpret_cast<const float2*>(gw);
  int p = 0;
  for (int it = 0; it < N_TOK / 256; ++it) {   // 32 iters
    int4 v = ch4[it * 64 + lane];
#pragma unroll
    for (int s = 0; s < 4; ++s) {
      int c = (s == 0) ? v.x : (s == 1) ? v.y : (s == 2) ? v.z : v.w;
      int t = it * 256 + 4 * lane + s;
      unsigned long long m0 = __ballot((c & 255) == w);
      if ((c & 255) == w) {
        int r = p + __popcll(m0 & lmask);
        toklist[w * N_TOK + r] = t;
        wlist[w * N_TOK + r] = gw2[t].x;
      }
      p += __popcll(m0);
      unsigned long long m1 = __ballot(((c >> 8) & 255) == w);
      if (((c >> 8) & 255) == w) {
        int r = p + __popcll(m1 & lmask);
        toklist[w * N_TOK + r] = t;
        wlist[w * N_TOK + r] = gw2[t].y;
      }
      p += __popcll(m1);
    }
  }
  if (lane == 0) cnt[w] = p;
}

// ---------------- grouped GEMM: C = relu(Xg @ We^T + be) * wt, atomicAdd to out ----
// m97 structure: 128x128 tile, BK=64, 4 waves (2x2), single-buffered 33 KB LDS ->
// 4 resident blocks/CU (cross-block overlap hides barrier drains). T5 setprio(1)
// around the compute cluster: co-resident blocks are at DIFFERENT phases
// (independent, not barrier-locked) -> scheduler favors MFMA-phase waves (m191
// regime, not m190's lockstep null). 8192 blocks: XCD-chunked (expert e -> XCD e),
// 4x4 supergroups; live blocks (slot<16 when cnt~2048) are p<2048, dispatched first.
__global__ __launch_bounds__(256, 4) void moe_gemm(
    const __hip_bfloat16* __restrict__ xb, const __hip_bfloat16* __restrict__ wb,
    const float* __restrict__ be, const int* __restrict__ cnt,
    const int* __restrict__ toklist, const float* __restrict__ wlist,
    float* __restrict__ out) {
  const int p = blockIdx.x;                  // 0..8191
  const int l = (p & 7) * 1024 + (p >> 3);   // bijective XCD-chunked remap
  const int e = l >> 10;                     // expert -> XCD
  const int w = l & 1023;
  const int sg = w >> 4, dd = w & 15;        // 64 supergroups of 16 blocks
  const int slot = (sg >> 2) * 4 + (dd >> 2);  // 0..63 row-slot
  const int ct   = (sg & 3) * 4 + (dd & 3);    // 0..15 col-tile
  const int ce = cnt[e];
  const int row0 = slot * BM;
  if (row0 >= ce) return;                    // uniform early-exit
  const int bn0 = ct * BN;

  __shared__ __align__(16) __hip_bfloat16 sA[BM * BK];  // 16 KB
  __shared__ __align__(16) __hip_bfloat16 sB[BN * BK];  // 16 KB
  __shared__ int   sTok[BM];
  __shared__ float sWt[BM];

  const int tid = threadIdx.x;
  if (tid < BM) {
    int r = row0 + tid;
    bool valid = r < ce;
    sTok[tid] = valid ? toklist[e * N_TOK + r] : 0;
    sWt[tid]  = valid ? wlist[e * N_TOK + r] : 0.f;
  }
  __syncthreads();

  // Staging sources. LDS dest LINEAR (global_load_lds rule); XOR granule swizzle
  // (g = pg ^ (r&7), 16B granules in 128B rows) on the GLOBAL source; reads apply
  // the same XOR (involution; verified rounds 1-7: pass, 0 bank conflicts).
  const char* srcA[4];
  const char* srcB[4];
#pragma unroll
  for (int n = 0; n < 4; ++n) {
    int cch = tid + 256 * n;  // 16B chunk id 0..1023
    int r = cch >> 3;         // tile row 0..127
    int pg = cch & 7;         // physical granule
    int g = pg ^ (r & 7);     // logical (source) granule
    srcA[n] = (const char*)(xb + (size_t)sTok[r] * DIM + g * 8);
    srcB[n] = (const char*)(wb + (size_t)(e * DIM + bn0 + r) * DIM + g * 8);
  }

  const int lane = tid & 63;
  const int wv = tid >> 6;
  const int wr = (wv >> 1) * 64;   // wave row offset (2x2 waves)
  const int wc = (wv & 1) * 64;

  f32x4 acc[4][4];
#pragma unroll
  for (int mi = 0; mi < 4; ++mi)
#pragma unroll
    for (int ni = 0; ni < 4; ++ni)
      acc[mi][ni] = (f32x4){0.f, 0.f, 0.f, 0.f};

  for (int kt = 0; kt < KT; ++kt) {
    const int koff = kt * (BK * 2);   // bytes along K
#pragma unroll
    for (int n = 0; n < 4; ++n) {
      gload_lds16(srcA[n] + koff, (char*)sA + (tid + 256 * n) * 16);
      gload_lds16(srcB[n] + koff, (char*)sB + (tid + 256 * n) * 16);
    }
    __syncthreads();   // drains vmcnt(0); other resident blocks hide the stall
    __builtin_amdgcn_s_setprio(1);   // T5: favor compute-phase block on the SIMDs
#pragma unroll
    for (int ks = 0; ks < 2; ++ks) {
      const int gbase = ks * 4 + (lane >> 4);
      short8 bfr[4];
#pragma unroll
      for (int i = 0; i < 4; ++i) {
        int rB = wc + i * 16 + (lane & 15);
        bfr[i] = *(const short8*)((const char*)sB + rB * 128 +
                                  ((gbase ^ (rB & 7)) << 4));
      }
#pragma unroll
      for (int mi = 0; mi < 4; ++mi) {
        int rA = wr + mi * 16 + (lane & 15);
        short8 a = *(const short8*)((const char*)sA + rA * 128 +
                                    ((gbase ^ (rA & 7)) << 4));
#pragma unroll
        for (int ni = 0; ni < 4; ++ni)
          acc[mi][ni] = __builtin_amdgcn_mfma_f32_16x16x32_bf16(
              a, bfr[ni], acc[mi][ni], 0, 0, 0);
      }
    }
    __builtin_amdgcn_s_setprio(0);
    __syncthreads();   // all waves done reading before next stage overwrites
  }

  // epilogue: bias + relu + gate-weight, atomicAdd into out (zeroed by prep).
  // C/D layout (m89-verified): col = lane&15, row = (lane>>4)*4 + reg.
  const int cvalid = ce - row0;
#pragma unroll
  for (int mi = 0; mi < 4; ++mi) {
    int lr0 = wr + mi * 16 + (lane >> 4) * 4;
#pragma unroll
    for (int ni = 0; ni < 4; ++ni) {
      int col = bn0 + wc + ni * 16 + (lane & 15);
      float bv = be[e * DIM + col];
#pragma unroll
      for (int q = 0; q < 4; ++q) {
        int lr = lr0 + q;
        if (lr < cvalid) {
          float v = fmaxf(acc[mi][ni][q] + bv, 0.f) * sWt[lr];
          atomicAdd(out + (size_t)sTok[lr] * DIM + col, v);
        }
      }
    }
  }
}

extern "C" void kernel_launch(void* const* d_in, const int* in_sizes, int n_in,
                              void* d_out, int out_size, void* d_ws, size_t ws_size,
                              hipStream_t stream) {
  const float* x  = (const float*)d_in[0];
  const float* We = (const float*)d_in[1];
  const float* be = (const float*)d_in[2];
  const float* Wg = (const float*)d_in[3];
  const float* bg = (const float*)d_in[4];
  float* out = (float*)d_out;
  char* ws = (char*)d_ws;

  int*   cnt = (int*)(ws + OFF_CNT);
  int*   ch  = (int*)(ws + OFF_CH);
  float* gw  = (float*)(ws + OFF_GW);
  int*   tok = (int*)(ws + OFF_TOK);
  float* wl  = (float*)(ws + OFF_WL);
  __hip_bfloat16* xb = (__hip_bfloat16*)(ws + OFF_XB);
  __hip_bfloat16* wb = (__hip_bfloat16*)(ws + OFF_WB);

  prep_kernel<<<4096, 256, 0, stream>>>(x, We, Wg, bg, xb, wb, ch, gw, out);
  build_lists<<<1, 512, 0, stream>>>(ch, gw, cnt, tok, wl);
  moe_gemm<<<8192, 256, 0, stream>>>(xb, wb, be, cnt, tok, wl, out);
}